// Round 10
// baseline (107.849 us; speedup 1.0000x reference)
//
#include <hip/hip_runtime.h>
#include <hip/hip_bf16.h>
#include <math.h>

typedef __attribute__((ext_vector_type(4))) float f32x4;
typedef __bf16 bf16x8 __attribute__((ext_vector_type(8)));
typedef unsigned short u16;
typedef u16 u16x8 __attribute__((ext_vector_type(8)));
typedef void __attribute__((address_space(1))) * as1p;
typedef void __attribute__((address_space(3))) * as3p;

#define SCHEDB() __builtin_amdgcn_sched_barrier(0)

__device__ __forceinline__ unsigned short f2bf(float f) {
    union { float f; unsigned int u; } v; v.f = f;
    unsigned int u = v.u;
    u += 0x7fffu + ((u >> 16) & 1u);   // RNE
    return (unsigned short)(u >> 16);
}

__device__ __forceinline__ float bf2f(unsigned short b) {
    union { unsigned int u; float f; } v;
    v.u = ((unsigned int)b) << 16;
    return v.f;
}

__device__ __forceinline__ float fast_tanh(float v) {
    float vc = fminf(fmaxf(v, -15.f), 15.f);
    float e = __expf(2.f * vc);
    return (e - 1.f) / (e + 1.f);
}

// ---------- prepass: 3 weight transposes fp32 [1024][512] -> bf16 [512][1024] ----------
__global__ void prepw_k(const float* __restrict__ s0, const float* __restrict__ s1,
                        const float* __restrict__ s2, u16* __restrict__ d0,
                        u16* __restrict__ d1, u16* __restrict__ d2) {
    __shared__ float t[32][33];
    int b = blockIdx.x;
    int z = b >> 9;
    int rem = b & 511;
    const float* src = (z == 0) ? s0 : (z == 1) ? s1 : s2;
    u16* dst = (z == 0) ? d0 : (z == 1) ? d1 : d2;
    int n0 = (rem & 15) * 32;
    int k0 = (rem >> 4) * 32;
    int tid = threadIdx.x;
    int tx = tid & 31, ty = tid >> 5;
#pragma unroll
    for (int i = 0; i < 4; ++i)
        t[ty + i * 8][tx] = src[(size_t)(k0 + ty + i * 8) * 512 + n0 + tx];
    __syncthreads();
#pragma unroll
    for (int i = 0; i < 4; ++i)
        dst[(size_t)(n0 + ty + i * 8) * 1024 + k0 + tx] = f2bf(t[tx][ty + i * 8]);
}

// ---------- W staging: 64 cols x 64 k bf16 tile (8 KB), per-WAVE, no barriers ----------
// linear LDS dest (gload_lds), inverse-swizzled global source; 128 B rows, row&7 swizzle
__device__ __forceinline__ void stageW(const u16* Wt, int ncol, int ks, u16* buf, int l) {
#pragma unroll
    for (int ld = 0; ld < 8; ++ld) {
        int ob = ld * 1024;                          // wave-uniform byte base
        int o = ob + l * 16;
        int row = o >> 7;
        int cb = (o & 127) ^ ((row & 7) << 4);
        const u16* gp = Wt + (size_t)(ncol + row) * 1024 + ks * 64 + (cb >> 1);
        __builtin_amdgcn_global_load_lds((as1p)(void*)gp, (as3p)(void*)(buf + (ob >> 1)), 16, 0, 0);
    }
}

__device__ __forceinline__ bf16x8 ldW(const u16* buf, int r, int kb) {
    return *(const bf16x8*)((const char*)buf + (r << 7) + (kb ^ ((r & 7) << 4)));
}

// A tile [32][1024] bf16, 2048 B rows, row&7 swizzle (written swizzled by this kernel)
__device__ __forceinline__ bf16x8 ldA(const u16* lds, int row, int kb) {
    return *(const bf16x8*)((const char*)lds + (row << 11) + (kb ^ ((row & 7) << 4)));
}

// one K-step (64 k): 4 A-reads + 8 W-reads + 32 MFMA (wave computes 32 rows x 64 cols)
__device__ __forceinline__ void cstep(const u16* lds, const u16* buf, int s,
                                      int fr, int kbb, f32x4 (&acc)[2][4]) {
#pragma unroll
    for (int q = 0; q < 2; ++q) {
        int kb = q * 64 + kbb;
        bf16x8 a0 = ldA(lds, fr, s * 128 + kb);
        bf16x8 a1 = ldA(lds, 16 + fr, s * 128 + kb);
        bf16x8 b[4];
#pragma unroll
        for (int n = 0; n < 4; ++n) b[n] = ldW(buf, n * 16 + fr, kb);
#pragma unroll
        for (int n = 0; n < 4; ++n) {
            acc[0][n] = __builtin_amdgcn_mfma_f32_16x16x32_bf16(a0, b[n], acc[0][n], 0, 0, 0);
            acc[1][n] = __builtin_amdgcn_mfma_f32_16x16x32_bf16(a1, b[n], acc[1][n], 0, 0, 0);
        }
    }
}

// one 64-col output panel over K=1024: 16 steps, 3-buf ring, counted vmcnt, NO barriers
__device__ __forceinline__ void panel(const u16* lds, const u16* Wt, int ncol,
                                      u16* wb, int l, int fr, int kbb, f32x4 (&acc)[2][4]) {
#pragma unroll
    for (int m = 0; m < 2; ++m)
#pragma unroll
        for (int n = 0; n < 4; ++n) acc[m][n] = (f32x4){0.f, 0.f, 0.f, 0.f};
    u16 *B0 = wb, *B1 = wb + 4096, *B2 = wb + 8192;
    stageW(Wt, ncol, 0, B0, l);
    stageW(Wt, ncol, 1, B1, l);
    for (int s = 0; s < 14; ++s) {
        stageW(Wt, ncol, s + 2, B2, l);                     // 2-tile lookahead
        asm volatile("s_waitcnt vmcnt(16)" ::: "memory");   // tile s landed; s+1,s+2 in flight
        SCHEDB();
        cstep(lds, B0, s, fr, kbb, acc);
        u16* t = B0; B0 = B1; B1 = B2; B2 = t;
    }
    asm volatile("s_waitcnt vmcnt(8)" ::: "memory"); SCHEDB();
    cstep(lds, B0, 14, fr, kbb, acc);
    asm volatile("s_waitcnt vmcnt(0)" ::: "memory"); SCHEDB();
    cstep(lds, B1, 15, fr, kbb, acc);
}

// ================= fused GRU: one 32-row strip per block =================
// LDS: A [32][1024] bf16 = 64 KB @0; per-wave W: 3 bufs x 8 KB at 32768 + w*12288 (u16).
// Total 160 KB -> 1 block/CU, 4 waves (1/SIMD). Wave w owns cols [w*128, w*128+128) of each gate.
__global__ __launch_bounds__(256, 1) void gru_k(
    const float* __restrict__ x, const float* __restrict__ hprev,
    const u16* __restrict__ Wzt, const u16* __restrict__ Wrt, const u16* __restrict__ Wht,
    const float* __restrict__ ub, const float* __restrict__ rb_, const float* __restrict__ hbv,
    float* __restrict__ out) {
    extern __shared__ u16 lds[];
    const int tid = threadIdx.x;
    const int l = tid & 63, w = tid >> 6;
    const int fr = l & 15;
    const int kbb = (l >> 4) << 4;       // k-group byte offset within 64 B half
    const int rquad = (l >> 4) << 2;     // C/D row quad base
    const int m0 = blockIdx.x * 32;
    const int wcol = w * 128;
    u16* wb = lds + 32768 + w * 12288;   // wave-private W ring

    // === A-stage: [x|h] fp32 -> swizzled bf16 LDS (once) ===
#pragma unroll
    for (int it = 0; it < 16; ++it) {
        int g = it * 256 + tid;          // 32 rows x 128 groups of 8 elems
        int row = g >> 7, cg = g & 127;
        const float* src = (cg < 64) ? &x[(size_t)(m0 + row) * 512 + cg * 8]
                                     : &hprev[(size_t)(m0 + row) * 512 + (cg - 64) * 8];
        float4 f0 = *(const float4*)src;
        float4 f1 = *(const float4*)(src + 4);
        u16x8 v;
        v[0] = f2bf(f0.x); v[1] = f2bf(f0.y); v[2] = f2bf(f0.z); v[3] = f2bf(f0.w);
        v[4] = f2bf(f1.x); v[5] = f2bf(f1.y); v[6] = f2bf(f1.z); v[7] = f2bf(f1.w);
        int byte = row * 2048 + ((cg * 16) ^ ((row & 7) << 4));
        *(u16x8*)((char*)lds + byte) = v;
    }
    __syncthreads();

    f32x4 acc[2][4];
    unsigned int zp[2][2][4][2];    // z gate, bf16-packed pairs
    unsigned int rgp[2][2][4][2];   // rgh,   bf16-packed pairs

    // === z phase ===
#pragma unroll
    for (int p = 0; p < 2; ++p) {
        int ncol = wcol + p * 64;
        panel(lds, Wzt, ncol, wb, l, fr, kbb, acc);
#pragma unroll
        for (int n = 0; n < 4; ++n) {
            float bias = ub[ncol + n * 16 + fr];
#pragma unroll
            for (int m = 0; m < 2; ++m)
#pragma unroll
                for (int r = 0; r < 4; ++r) {
                    float s_ = 1.f / (1.f + __expf(-(acc[m][n][r] + bias)));
                    unsigned int bv = f2bf(s_);
                    if ((r & 1) == 0) zp[p][m][n][r >> 1] = bv;
                    else              zp[p][m][n][r >> 1] |= bv << 16;
                }
        }
    }

    // === r phase (reads h bf16 from A's H-slots for the product) ===
#pragma unroll
    for (int p = 0; p < 2; ++p) {
        int ncol = wcol + p * 64;
        panel(lds, Wrt, ncol, wb, l, fr, kbb, acc);
#pragma unroll
        for (int n = 0; n < 4; ++n) {
            float bias = rb_[ncol + n * 16 + fr];
            int kb = 2 * (512 + ncol + n * 16 + fr);
#pragma unroll
            for (int m = 0; m < 2; ++m)
#pragma unroll
                for (int r = 0; r < 4; ++r) {
                    int R = m * 16 + rquad + r;
                    u16 hv = *(const u16*)((const char*)lds + R * 2048 + (kb ^ ((R & 7) << 4)));
                    float s_ = 1.f / (1.f + __expf(-(acc[m][n][r] + bias)));
                    unsigned int bv = f2bf(s_ * bf2f(hv));
                    if ((r & 1) == 0) rgp[p][m][n][r >> 1] = bv;
                    else              rgp[p][m][n][r >> 1] |= bv << 16;
                }
        }
    }
    __syncthreads();   // all waves done reading H for z/r GEMMs
    // write rgh into A's H-slots (each wave its own cols — disjoint)
#pragma unroll
    for (int p = 0; p < 2; ++p)
#pragma unroll
        for (int n = 0; n < 4; ++n) {
            int kb = 2 * (512 + wcol + p * 64 + n * 16 + fr);
#pragma unroll
            for (int m = 0; m < 2; ++m)
#pragma unroll
                for (int r = 0; r < 4; ++r) {
                    int R = m * 16 + rquad + r;
                    u16 bv = (u16)(rgp[p][m][n][r >> 1] >> (16 * (r & 1)));
                    *(u16*)((char*)lds + R * 2048 + (kb ^ ((R & 7) << 4))) = bv;
                }
        }
    __syncthreads();   // rgh visible to all waves

    // === h~ phase: A = [x | rgh]; blend with fp32 h and z from regs ===
#pragma unroll
    for (int p = 0; p < 2; ++p) {
        int ncol = wcol + p * 64;
        panel(lds, Wht, ncol, wb, l, fr, kbb, acc);
#pragma unroll
        for (int n = 0; n < 4; ++n) {
            float bias = hbv[ncol + n * 16 + fr];
#pragma unroll
            for (int m = 0; m < 2; ++m)
#pragma unroll
                for (int r = 0; r < 4; ++r) {
                    int R = m * 16 + rquad + r;
                    size_t gidx = (size_t)(m0 + R) * 512 + ncol + n * 16 + fr;
                    float t = fast_tanh(acc[m][n][r] + bias);
                    float h0 = hprev[gidx];
                    float z = bf2f((u16)(zp[p][m][n][r >> 1] >> (16 * (r & 1))));
                    out[gidx] = h0 + z * (t - h0);
                }
        }
    }
}

extern "C" void kernel_launch(void* const* d_in, const int* in_sizes, int n_in,
                              void* d_out, int out_size, void* d_ws, size_t ws_size,
                              hipStream_t stream) {
    const float* x  = (const float*)d_in[0];
    const float* h  = (const float*)d_in[1];
    const float* wz = (const float*)d_in[2];
    const float* wr = (const float*)d_in[3];
    const float* wh = (const float*)d_in[4];
    const float* ub = (const float*)d_in[5];
    const float* rb = (const float*)d_in[6];
    const float* hb = (const float*)d_in[7];
    float* out = (float*)d_out;

    char* ws = (char*)d_ws;
    size_t off = 0;
    u16* Wzt = (u16*)(ws + off); off += (size_t)512 * 1024 * 2;   // 1 MB
    u16* Wrt = (u16*)(ws + off); off += (size_t)512 * 1024 * 2;   // 1 MB
    u16* Wht = (u16*)(ws + off); off += (size_t)512 * 1024 * 2;   // 1 MB

    hipFuncSetAttribute((const void*)gru_k, hipFuncAttributeMaxDynamicSharedMemorySize, 163840);

    prepw_k<<<1536, 256, 0, stream>>>(wz, wr, wh, Wzt, Wrt, Wht);
    gru_k<<<512, 256, 163840, stream>>>(x, h, Wzt, Wrt, Wht, ub, rb, hb, out);
}

// Round 11
// 104.931 us; speedup vs baseline: 1.0278x; 1.0278x over previous
//
#include <hip/hip_runtime.h>
#include <hip/hip_bf16.h>
#include <math.h>

typedef __attribute__((ext_vector_type(4))) float f32x4;
typedef __attribute__((ext_vector_type(8))) float f32x8;
typedef __bf16 bf16x8 __attribute__((ext_vector_type(8)));
typedef unsigned short u16;
typedef u16 u16x8 __attribute__((ext_vector_type(8)));
typedef void __attribute__((address_space(1))) * as1p;
typedef void __attribute__((address_space(3))) * as3p;

#define SCHEDB() __builtin_amdgcn_sched_barrier(0)
#define BAR()    __builtin_amdgcn_s_barrier()
#define VM4()    asm volatile("s_waitcnt vmcnt(4)" ::: "memory")
#define VM0()    asm volatile("s_waitcnt vmcnt(0)" ::: "memory")

__device__ __forceinline__ unsigned short f2bf(float f) {
    union { float f; unsigned int u; } v; v.f = f;
    unsigned int u = v.u;
    u += 0x7fffu + ((u >> 16) & 1u);   // RNE
    return (unsigned short)(u >> 16);
}

__device__ __forceinline__ float bf2f(unsigned short b) {
    union { unsigned int u; float f; } v;
    v.u = ((unsigned int)b) << 16;
    return v.f;
}

__device__ __forceinline__ float fast_tanh(float v) {
    float vc = fminf(fmaxf(v, -15.f), 15.f);
    float e = __expf(2.f * vc);
    return (e - 1.f) / (e + 1.f);
}

// ---------- prepass: cvt x,h -> bf16 AND 3 weight transposes (unchanged, R8/R9-proven) ----------
__global__ void prep_k(const float* __restrict__ x, const float* __restrict__ h,
                       const float* __restrict__ wz, const float* __restrict__ wrr,
                       const float* __restrict__ wh,
                       u16* __restrict__ xb, u16* __restrict__ hb,
                       u16* __restrict__ wzt, u16* __restrict__ wrt, u16* __restrict__ wht) {
    __shared__ float t[32][33];
    int bid = blockIdx.x;
    int tid = threadIdx.x;
    if (bid < 2048) {
        const int n4 = 16384 * 512 / 4;
        int i = bid * 256 + tid;
        const int stride = 2048 * 256;
        const float4* x4 = (const float4*)x;
        const float4* h4 = (const float4*)h;
        ushort4* xb4 = (ushort4*)xb;
        ushort4* hb4 = (ushort4*)hb;
        for (; i < n4; i += stride) {
            float4 v = x4[i];
            xb4[i] = make_ushort4(f2bf(v.x), f2bf(v.y), f2bf(v.z), f2bf(v.w));
            float4 w = h4[i];
            hb4[i] = make_ushort4(f2bf(w.x), f2bf(w.y), f2bf(w.z), f2bf(w.w));
        }
    } else {
        int b = bid - 2048;
        int z = b >> 9;
        int rem = b & 511;
        const float* src = (z == 0) ? wz : (z == 1) ? wrr : wh;
        u16* dst = (z == 0) ? wzt : (z == 1) ? wrt : wht;
        int n0 = (rem & 15) * 32;
        int k0 = (rem >> 4) * 32;
        int tx = tid & 31, ty = tid >> 5;
#pragma unroll
        for (int i = 0; i < 4; ++i)
            t[ty + i * 8][tx] = src[(size_t)(k0 + ty + i * 8) * 512 + n0 + tx];
        __syncthreads();
#pragma unroll
        for (int i = 0; i < 4; ++i)
            dst[(size_t)(n0 + ty + i * 8) * 1024 + k0 + tx] = f2bf(t[tx][ty + i * 8]);
    }
}

// ================= 256x256 8-phase template, 512 threads (8 waves, 2M x 4N) =================
// LDS regions (u16 offsets): buf b in {0,1}; region r: 0=A0,1=A1,2=B0,3=B1; each 128x64 bf16 = 16 KB.
#define RGN(L, b, r) ((L) + (b) * 32768 + (r) * 8192)

// stage one 128x64 half-tile: linear LDS dest, inverse-swizzled global src (proven pair, conflicts=0)
__device__ __forceinline__ void stage_half512(const u16* g, int gstride, u16* region, int tid) {
#pragma unroll
    for (int rd = 0; rd < 2; ++rd) {
        int ob = rd * 8192 + ((tid >> 6) << 10);    // wave-uniform byte base (8 waves x 1 KB)
        int o = ob + ((tid & 63) << 4);
        int row = o >> 7;
        int cb = (o & 127) ^ ((row & 7) << 4);
        const u16* gp = g + (size_t)row * gstride + (cb >> 1);
        __builtin_amdgcn_global_load_lds((as1p)(void*)gp, (as3p)(void*)(region + (ob >> 1)), 16, 0, 0);
    }
}

__device__ __forceinline__ bf16x8 ld_frag(const u16* region, int r, int kb) {
    int byte = (r << 7) + (kb ^ ((r & 7) << 4));
    return *(const bf16x8*)((const char*)region + byte);
}

__device__ __forceinline__ void rdA(const u16* rg, int base_r, int kbb, bf16x8 (&a)[4][2]) {
#pragma unroll
    for (int mf = 0; mf < 4; ++mf)
#pragma unroll
        for (int q = 0; q < 2; ++q)
            a[mf][q] = ld_frag(rg, base_r + mf * 16, q * 64 + kbb);
}

__device__ __forceinline__ void rdB(const u16* rg, int base_r, int kbb, bf16x8 (&b)[2][2]) {
#pragma unroll
    for (int nf = 0; nf < 2; ++nf)
#pragma unroll
        for (int q = 0; q < 2; ++q)
            b[nf][q] = ld_frag(rg, base_r + nf * 16, q * 64 + kbb);
}

template<int MH, int NH>
__device__ __forceinline__ void mm16(f32x4 (&acc)[8][4], const bf16x8 (&a)[4][2],
                                     const bf16x8 (&b)[2][2]) {
    __builtin_amdgcn_s_setprio(1);
#pragma unroll
    for (int q = 0; q < 2; ++q)
#pragma unroll
        for (int mf = 0; mf < 4; ++mf)
#pragma unroll
            for (int nf = 0; nf < 2; ++nf)
                acc[MH * 4 + mf][NH * 2 + nf] = __builtin_amdgcn_mfma_f32_16x16x32_bf16(
                    a[mf][q], b[nf][q], acc[MH * 4 + mf][NH * 2 + nf], 0, 0, 0);
    __builtin_amdgcn_s_setprio(0);
}

// K-loop core: 16 tiles of BK=64. Stage schedule (region-safe, derived): during tile t,
// p1: A0(t+1)->buf[1-bt], p2: A1(t+1)->buf[1-bt], p3: B0(t+2)->buf[bt], p4: B1(t+2)->buf[bt].
// One vmcnt(4) per tile at p4-close retires exactly tile-(t+1)'s 4 halves; 2 halves stay in flight.
__device__ __forceinline__ void core8(const u16* AX, const u16* AH, const u16* BW,
                                      u16* lds, int tid, f32x4 (&acc)[8][4]) {
    const int l = tid & 63, w = tid >> 6;
    const int wr = w >> 2, wc = w & 3;
    const int fr = l & 15, kbb = (l >> 4) << 4;
    const int br0 = (wc & 1) * 64 + fr;

    auto ap = [&](int t, int h) -> const u16* {
        const u16* base = (t < 8) ? (AX + t * 64) : (AH + (t - 8) * 64);
        return base + (size_t)h * (128 * 512);
    };
    auto bp = [&](int t, int h) -> const u16* {
        return BW + (size_t)h * (128 * 1024) + t * 64;
    };

    // prologue (mirrors steady state): t0.B0,B1 | t0.A0,A1, t1.B0,B1 ; vmcnt(4) retires t0's 4 halves
    stage_half512(bp(0, 0), 1024, RGN(lds, 0, 2), tid);
    stage_half512(bp(0, 1), 1024, RGN(lds, 0, 3), tid);
    stage_half512(ap(0, 0), 512,  RGN(lds, 0, 0), tid);
    stage_half512(ap(0, 1), 512,  RGN(lds, 0, 1), tid);
    stage_half512(bp(1, 0), 1024, RGN(lds, 1, 2), tid);
    stage_half512(bp(1, 1), 1024, RGN(lds, 1, 3), tid);
    VM4(); SCHEDB(); BAR();

    bf16x8 a[4][2], b0[2][2], b1[2][2];

    for (int t = 0; t < 14; ++t) {
        const int bt = t & 1;
        const u16* Ar = RGN(lds, bt, wr);
        const u16* Br = RGN(lds, bt, 2 + (wc >> 1));
        // p1: quadrant (0,0)
        rdA(Ar, fr, kbb, a);
        rdB(Br, br0, kbb, b0);
        stage_half512(ap(t + 1, 0), 512, RGN(lds, 1 - bt, 0), tid);
        BAR();
        mm16<0, 0>(acc, a, b0);
        BAR();
        // p2: quadrant (0,1)
        rdB(Br, br0 + 32, kbb, b1);
        stage_half512(ap(t + 1, 1), 512, RGN(lds, 1 - bt, 1), tid);
        BAR();
        mm16<0, 1>(acc, a, b1);
        BAR();
        // p3: quadrant (1,1)  (B0 region of current buf free after p2)
        rdA(Ar, 64 + fr, kbb, a);
        stage_half512(bp(t + 2, 0), 1024, RGN(lds, bt, 2), tid);
        BAR();
        mm16<1, 1>(acc, a, b1);
        BAR();
        // p4: quadrant (1,0)  (reuses b0 regs; B1 region free after p2)
        stage_half512(bp(t + 2, 1), 1024, RGN(lds, bt, 3), tid);
        BAR();
        mm16<1, 0>(acc, a, b0);
        VM4(); SCHEDB();
        BAR();
    }
    // t = 14: stage only t15.A halves; drain at close
    {
        const u16* Ar = RGN(lds, 0, wr);
        const u16* Br = RGN(lds, 0, 2 + (wc >> 1));
        rdA(Ar, fr, kbb, a); rdB(Br, br0, kbb, b0);
        stage_half512(ap(15, 0), 512, RGN(lds, 1, 0), tid);
        BAR(); mm16<0, 0>(acc, a, b0); BAR();
        rdB(Br, br0 + 32, kbb, b1);
        stage_half512(ap(15, 1), 512, RGN(lds, 1, 1), tid);
        BAR(); mm16<0, 1>(acc, a, b1); BAR();
        rdA(Ar, 64 + fr, kbb, a);
        BAR(); mm16<1, 1>(acc, a, b1); BAR();
        BAR(); mm16<1, 0>(acc, a, b0);
        VM0(); SCHEDB();
        BAR();
    }
    // t = 15: no stages, no waits
    {
        const u16* Ar = RGN(lds, 1, wr);
        const u16* Br = RGN(lds, 1, 2 + (wc >> 1));
        rdA(Ar, fr, kbb, a); rdB(Br, br0, kbb, b0);
        BAR(); mm16<0, 0>(acc, a, b0); BAR();
        rdB(Br, br0 + 32, kbb, b1);
        BAR(); mm16<0, 1>(acc, a, b1); BAR();
        rdA(Ar, 64 + fr, kbb, a);
        BAR(); mm16<1, 1>(acc, a, b1); BAR();
        BAR(); mm16<1, 0>(acc, a, b0);
    }
}

// scatter col-half ch of the block's 256x256 C into f32 tf[256][128] (reuses K-loop LDS)
__device__ __forceinline__ void scat(float* tf, const f32x4 (&acc)[8][4],
                                     int wr, int wc, int l, int ch) {
    if ((wc >> 1) != ch) return;
    int rb = wr * 128 + ((l >> 4) << 2);
    int cb = (wc & 1) * 64 + (l & 15);
#pragma unroll
    for (int mh = 0; mh < 2; ++mh)
#pragma unroll
        for (int mf = 0; mf < 4; ++mf)
#pragma unroll
            for (int nh = 0; nh < 2; ++nh)
#pragma unroll
                for (int nf = 0; nf < 2; ++nf) {
                    int row = rb + mh * 64 + mf * 16;
                    int col = cb + nh * 32 + nf * 16;
#pragma unroll
                    for (int r = 0; r < 4; ++r)
                        tf[(row + r) * 128 + col] = acc[mh * 4 + mf][nh * 2 + nf][r];
                }
}

// ================= gemm1: [X|H] @ [Wz|Wr]^T (N=1024, 256 blocks) -> zgb / rgh =================
__global__ __launch_bounds__(512, 1) void gemm1_k(
    const u16* __restrict__ Xb, const u16* __restrict__ Hb,
    const u16* __restrict__ Wzt, const u16* __restrict__ Wrt,
    const float* __restrict__ ub, const float* __restrict__ rb_,
    u16* __restrict__ zgb, u16* __restrict__ rgh) {
    extern __shared__ u16 lds[];
    const int tid = threadIdx.x;
    const int l = tid & 63, w = tid >> 6, wr = w >> 2, wc = w & 3;
    int swz = (blockIdx.x & 7) * 32 + (blockIdx.x >> 3);   // 256 blocks, bijective XCD swizzle
    int mb = swz >> 2, nb = swz & 3;
    int m0 = mb * 256, n0 = nb * 256;
    bool isZ = (n0 < 512);
    int cbase = isZ ? n0 : (n0 - 512);
    const u16* Wt = isZ ? Wzt : Wrt;

    f32x4 acc[8][4];
#pragma unroll
    for (int m = 0; m < 8; ++m)
#pragma unroll
        for (int n = 0; n < 4; ++n) acc[m][n] = (f32x4){0.f, 0.f, 0.f, 0.f};

    core8(Xb + (size_t)m0 * 512, Hb + (size_t)m0 * 512, Wt + (size_t)cbase * 1024,
          lds, tid, acc);

    float* tf = (float*)lds;
#pragma unroll
    for (int ch = 0; ch < 2; ++ch) {
        __syncthreads();
        scat(tf, acc, wr, wc, l, ch);
        __syncthreads();
#pragma unroll
        for (int it = 0; it < 8; ++it) {
            int chunk = it * 512 + tid;       // 256 rows x 16 groups
            int row = chunk >> 4;
            int c8 = (chunk & 15) << 3;
            f32x8 v8 = *(const f32x8*)&tf[row * 128 + c8];
            int gcol = cbase + ch * 128 + c8;
            size_t gbase = (size_t)(m0 + row) * 512 + gcol;
            if (isZ) {
                f32x8 bv = *(const f32x8*)&ub[gcol];
                u16x8 o;
#pragma unroll
                for (int j = 0; j < 8; ++j)
                    o[j] = f2bf(1.f / (1.f + __expf(-(v8[j] + bv[j]))));
                *(u16x8*)&zgb[gbase] = o;
            } else {
                f32x8 bv = *(const f32x8*)&rb_[gcol];
                u16x8 h8 = *(const u16x8*)&Hb[gbase];
                u16x8 o;
#pragma unroll
                for (int j = 0; j < 8; ++j) {
                    float s = 1.f / (1.f + __expf(-(v8[j] + bv[j])));
                    o[j] = f2bf(s * bf2f(h8[j]));
                }
                *(u16x8*)&rgh[gbase] = o;
            }
        }
    }
}

// ================= gemm2: [X|rgh] @ Wh^T (N=512, 128 blocks) -> out fp32 =================
__global__ __launch_bounds__(512, 1) void gemm2_k(
    const u16* __restrict__ Xb, const u16* __restrict__ rgh, const u16* __restrict__ Wht,
    const float* __restrict__ hp, const u16* __restrict__ zgb, const float* __restrict__ hbv,
    float* __restrict__ out) {
    extern __shared__ u16 lds[];
    const int tid = threadIdx.x;
    const int l = tid & 63, w = tid >> 6, wr = w >> 2, wc = w & 3;
    int swz = (blockIdx.x & 7) * 16 + (blockIdx.x >> 3);   // 128 blocks, bijective
    int mb = swz >> 1, nb = swz & 1;
    int m0 = mb * 256, n0 = nb * 256;

    f32x4 acc[8][4];
#pragma unroll
    for (int m = 0; m < 8; ++m)
#pragma unroll
        for (int n = 0; n < 4; ++n) acc[m][n] = (f32x4){0.f, 0.f, 0.f, 0.f};

    core8(Xb + (size_t)m0 * 512, rgh + (size_t)m0 * 512, Wht + (size_t)n0 * 1024,
          lds, tid, acc);

    float* tf = (float*)lds;
#pragma unroll
    for (int ch = 0; ch < 2; ++ch) {
        __syncthreads();
        scat(tf, acc, wr, wc, l, ch);
        __syncthreads();
#pragma unroll
        for (int it = 0; it < 8; ++it) {
            int chunk = it * 512 + tid;
            int row = chunk >> 4;
            int c8 = (chunk & 15) << 3;
            f32x8 v8 = *(const f32x8*)&tf[row * 128 + c8];
            int gcol = n0 + ch * 128 + c8;
            size_t gbase = (size_t)(m0 + row) * 512 + gcol;
            f32x8 bv = *(const f32x8*)&hbv[gcol];
            f32x8 h8 = *(const f32x8*)&hp[gbase];
            u16x8 z8 = *(const u16x8*)&zgb[gbase];
            f32x8 o;
#pragma unroll
            for (int j = 0; j < 8; ++j) {
                float t = fast_tanh(v8[j] + bv[j]);
                float z = bf2f(z8[j]);
                o[j] = h8[j] + z * (t - h8[j]);
            }
            *(f32x8*)&out[gbase] = o;
        }
    }
}

extern "C" void kernel_launch(void* const* d_in, const int* in_sizes, int n_in,
                              void* d_out, int out_size, void* d_ws, size_t ws_size,
                              hipStream_t stream) {
    const float* x  = (const float*)d_in[0];
    const float* h  = (const float*)d_in[1];
    const float* wz = (const float*)d_in[2];
    const float* wr = (const float*)d_in[3];
    const float* wh = (const float*)d_in[4];
    const float* ub = (const float*)d_in[5];
    const float* rb = (const float*)d_in[6];
    const float* hb = (const float*)d_in[7];
    float* out = (float*)d_out;

    const int B = 16384;
    char* ws = (char*)d_ws;
    size_t off = 0;
    u16* Xb  = (u16*)(ws + off); off += (size_t)B * 512 * 2;      // 16 MB
    u16* Hb  = (u16*)(ws + off); off += (size_t)B * 512 * 2;      // 16 MB
    u16* Wzt = (u16*)(ws + off); off += (size_t)512 * 1024 * 2;   // 1 MB
    u16* Wrt = (u16*)(ws + off); off += (size_t)512 * 1024 * 2;   // 1 MB
    u16* Wht = (u16*)(ws + off); off += (size_t)512 * 1024 * 2;   // 1 MB
    u16* rgh = (u16*)(ws + off); off += (size_t)B * 512 * 2;      // 16 MB
    u16* zgb = (u16*)(ws + off); off += (size_t)B * 512 * 2;      // 16 MB

    hipFuncSetAttribute((const void*)gemm1_k, hipFuncAttributeMaxDynamicSharedMemorySize, 131072);
    hipFuncSetAttribute((const void*)gemm2_k, hipFuncAttributeMaxDynamicSharedMemorySize, 131072);

    prep_k<<<2048 + 1536, 256, 0, stream>>>(x, h, wz, wr, wh, Xb, Hb, Wzt, Wrt, Wht);

    gemm1_k<<<256, 512, 131072, stream>>>(Xb, Hb, Wzt, Wrt, ub, rb, zgb, rgh);
    gemm2_k<<<128, 512, 131072, stream>>>(Xb, rgh, Wht, h, zgb, hb, out);
}